// Round 6
// baseline (353.890 us; speedup 1.0000x reference)
//
#include <hip/hip_runtime.h>
#include <hip/hip_bf16.h>

typedef unsigned short u16;
typedef unsigned int   u32;
typedef __bf16 bf16x8 __attribute__((ext_vector_type(8)));
typedef float  f32x4  __attribute__((ext_vector_type(4)));

#define BB 2
#define TT 8192
#define DD 512
#define HH 8
#define WW 256
#define DH 64
#define NX 8388608   // 16384*512
#define NW 262144    // 512*512

__device__ __forceinline__ float b2f(u16 u) {
    unsigned int x = ((unsigned int)u) << 16;
    return __builtin_bit_cast(float, x);
}
__device__ __forceinline__ u16 f2b(float f) {
    __bf16 h = (__bf16)f;
    return __builtin_bit_cast(u16, h);
}
__device__ __forceinline__ bf16x8 ldsfrag(const u16* p) {
    return *(const bf16x8*)p;
}
__device__ __forceinline__ f32x4 mfma16(bf16x8 a, bf16x8 b, f32x4 c) {
    return __builtin_amdgcn_mfma_f32_16x16x32_bf16(a, b, c, 0, 0, 0);
}

// ---- convert all 9 inputs to bf16 in workspace (vectorized, 8 elem/thread).
// dtype flag computed per-block from x's first 2048 u16 (deterministic);
// block 0 persists it for the O-proj epilogue.
__device__ __forceinline__ void cvt8(const void* s, u16* d, long i, int f) {
    if (f) {
        const u32* sp = (const u32*)s + i;
        uint4 a = *(const uint4*)(sp);
        uint4 b = *(const uint4*)(sp + 4);
        u16 o[8];
        o[0] = f2b(__builtin_bit_cast(float, a.x));
        o[1] = f2b(__builtin_bit_cast(float, a.y));
        o[2] = f2b(__builtin_bit_cast(float, a.z));
        o[3] = f2b(__builtin_bit_cast(float, a.w));
        o[4] = f2b(__builtin_bit_cast(float, b.x));
        o[5] = f2b(__builtin_bit_cast(float, b.y));
        o[6] = f2b(__builtin_bit_cast(float, b.z));
        o[7] = f2b(__builtin_bit_cast(float, b.w));
        *(uint4*)(d + i) = *(const uint4*)o;
    } else {
        *(uint4*)(d + i) = *(const uint4*)((const u16*)s + i);
    }
}

__global__ void convert_all(const void* x, const void* Wq, const void* bq,
                            const void* Wk, const void* bk, const void* Wv,
                            const void* bv, const void* Wo, const void* bo,
                            u16* __restrict__ xb, u16* __restrict__ Wcat,
                            u16* __restrict__ Wob, u16* __restrict__ bcat,
                            u16* __restrict__ bob, int* __restrict__ flagw)
{
    __shared__ int sflag;
    const int tid = threadIdx.x;
    if (tid == 0) sflag = 0;
    __syncthreads();
    int mybad = 0;
    for (int i = tid; i < 2048; i += 256) {
        float v = b2f(((const u16*)x)[i]);
        if (!(fabsf(v) < 100.f)) mybad = 1;   // fp32 mantissa halves look wild
    }
    if (mybad) atomicOr(&sflag, 1);
    __syncthreads();
    const int f = sflag ? 1 : 0;
    if (blockIdx.x == 0 && tid == 0) *flagw = f;

    long i = ((long)blockIdx.x * 256 + tid) * 8;
    if (i < NX)            { cvt8(x,  xb,           i, f); return; }
    i -= NX;
    if (i < NW)            { cvt8(Wq, Wcat,         i, f); return; }
    i -= NW;
    if (i < NW)            { cvt8(Wk, Wcat + NW,    i, f); return; }
    i -= NW;
    if (i < NW)            { cvt8(Wv, Wcat + 2*NW,  i, f); return; }
    i -= NW;
    if (i < NW)            { cvt8(Wo, Wob,          i, f); return; }
    i -= NW;
    if (i < 512)           { cvt8(bq, bcat,         i, f); return; }
    i -= 512;
    if (i < 512)           { cvt8(bk, bcat + 512,   i, f); return; }
    i -= 512;
    if (i < 512)           { cvt8(bv, bcat + 1024,  i, f); return; }
    i -= 512;
    if (i < 512)           { cvt8(bo, bob,          i, f); }
}

// 128x128-tile GEMM, BK=64, 512 threads = 8 waves (2-way M x 4-way N, 64x32
// acc each). Register-prefetch pipeline: next tile's global loads are issued
// BEFORE compute of the current tile, so the vmcnt drain at the next barrier
// waits on loads that already had a full compute phase. 32 KB LDS (single
// buffer) keeps 4 blocks/CU = 32 waves/CU.
// out[m,n] = sum_k A[m,k]*Bw[n,k] + bias[n]; K=512 fixed.
// mode 0 (fused QKV, N=1536): seg0->out0 (Q [t][h*64+d]), seg1->out1 (K same),
//   seg2->out2 (V TRANSPOSED: [(b*8+h)*64+d][t]).
// mode 1 (O-proj): out0, fp32 if *flagp else bf16.
__global__ __launch_bounds__(512, 4)
void gemm128(const u16* __restrict__ A, const u16* __restrict__ Bw,
             const u16* __restrict__ bias, void* __restrict__ out0,
             u16* __restrict__ out1, u16* __restrict__ out2,
             int mode, const int* __restrict__ flagp)
{
    __shared__ __align__(16) u16 AsF[128 * 64];
    __shared__ __align__(16) u16 BsF[128 * 64];

    const int tid  = threadIdx.x;
    const int lane = tid & 63;
    const int wv   = tid >> 6;           // 0..7
    const int col  = lane & 15;
    const int quad = lane >> 4;
    const int wm   = (wv & 1) * 64;      // M split 2
    const int wn   = (wv >> 1) * 32;     // N split 4
    const int m0   = blockIdx.x * 128;
    const int n0   = blockIdx.y * 128;

    const int ldr = lane >> 3;           // 0..7
    const int ldc = lane & 7;

    f32x4 acc[4][2] = {};

    uint4 ra[2], rb[2];
    // staged rows: r = (wv*2+i)*8 + ldr, source col group cb = ldc ^ (r&7)
    {
        #pragma unroll
        for (int i = 0; i < 2; i++) {
            const int r  = (wv * 2 + i) * 8 + ldr;
            const int cb = ldc ^ (r & 7);
            ra[i] = *(const uint4*)(A  + (size_t)(m0 + r) * 512 + cb * 8);
            rb[i] = *(const uint4*)(Bw + (size_t)(n0 + r) * 512 + cb * 8);
        }
    }

    for (int k0 = 0; k0 < 512; k0 += 64) {
        __syncthreads();   // prev iter's LDS readers done
        #pragma unroll
        for (int i = 0; i < 2; i++) {
            *(uint4*)&AsF[(wv * 2 + i) * 512 + lane * 8] = ra[i];
            *(uint4*)&BsF[(wv * 2 + i) * 512 + lane * 8] = rb[i];
        }
        __syncthreads();
        if (k0 + 64 < 512) {     // issue next tile's loads; land during compute
            #pragma unroll
            for (int i = 0; i < 2; i++) {
                const int r  = (wv * 2 + i) * 8 + ldr;
                const int cb = ldc ^ (r & 7);
                ra[i] = *(const uint4*)(A  + (size_t)(m0 + r) * 512 + k0 + 64 + cb * 8);
                rb[i] = *(const uint4*)(Bw + (size_t)(n0 + r) * 512 + k0 + 64 + cb * 8);
            }
        }
        #pragma unroll
        for (int kk = 0; kk < 2; kk++) {
            bf16x8 fa[4], fb[2];
            #pragma unroll
            for (int mi = 0; mi < 4; mi++)
                fa[mi] = ldsfrag(&AsF[(wm + mi * 16 + col) * 64 + ((kk * 4 + quad) ^ (col & 7)) * 8]);
            #pragma unroll
            for (int ni = 0; ni < 2; ni++)
                fb[ni] = ldsfrag(&BsF[(wn + ni * 16 + col) * 64 + ((kk * 4 + quad) ^ (col & 7)) * 8]);
            #pragma unroll
            for (int mi = 0; mi < 4; mi++)
                #pragma unroll
                for (int ni = 0; ni < 2; ni++)
                    acc[mi][ni] = mfma16(fa[mi], fb[ni], acc[mi][ni]);
        }
    }

    if (mode == 0) {
        #pragma unroll
        for (int ni = 0; ni < 2; ni++) {
            const int gn = n0 + wn + ni * 16 + col;     // 0..1535
            const float bv = b2f(bias[gn]);
            const int seg = gn >> 9;
            #pragma unroll
            for (int mi = 0; mi < 4; mi++) {
                const int gmb = m0 + wm + mi * 16 + quad * 4;
                if (seg < 2) {
                    u16* dst = (seg == 0) ? (u16*)out0 : out1;
                    #pragma unroll
                    for (int r = 0; r < 4; r++)
                        dst[(size_t)(gmb + r) * 512 + (gn & 511)] = f2b(acc[mi][ni][r] + bv);
                } else {
                    const int d = gn & 63, hh = (gn >> 6) & 7;
                    const int bb = gmb >> 13, t = gmb & 8191;
                    u16 pb[4];
                    #pragma unroll
                    for (int r = 0; r < 4; r++) pb[r] = f2b(acc[mi][ni][r] + bv);
                    uint2 pk;
                    pk.x = pb[0] | ((u32)pb[1] << 16);
                    pk.y = pb[2] | ((u32)pb[3] << 16);
                    *(uint2*)&out2[((size_t)(bb * 8 + hh) * 64 + d) * 8192 + t] = pk;
                }
            }
        }
    } else {
        const int outf32 = *flagp;
        #pragma unroll
        for (int ni = 0; ni < 2; ni++) {
            const int gn = n0 + wn + ni * 16 + col;
            const float bv = b2f(bias[gn]);
            #pragma unroll
            for (int mi = 0; mi < 4; mi++) {
                #pragma unroll
                for (int r = 0; r < 4; r++) {
                    const int gm = m0 + wm + mi * 16 + quad * 4 + r;
                    const float v = acc[mi][ni][r] + bv;
                    if (outf32) ((float*)out0)[(size_t)gm * 512 + gn] = v;
                    else        ((u16*)out0)[(size_t)gm * 512 + gn]  = f2b(v);
                }
            }
        }
    }
}

// Local attention v3: BARRIER-FREE. Block = (b,h,chunk), 8 waves x 32 queries.
// R4/R5 evidence: the 12x per-block barrier+drain convoy dominated (~40 us
// unexplained by any pipe model); occupancy/dbuf tweaks were near-neutral.
// Fix: K and VT A-fragments are coalesced 16B-per-lane patterns directly in
// global memory -> load fragments straight from global (L1/L2 serve the 8x
// intra-block redundancy), drop LDS staging and ALL __syncthreads. LDS keeps
// only the wave-private P tile (36 KB -> 4 blocks/CU = 32 waves/CU), every
// wave pipelines independently.
// Math identical to R5 (proven): no max-subtraction; S^T = K.Q^T; P via LDS
// round-trip; O^T = VT.P; V pre-transposed [b,h,d][t].
#define PSW 72
__global__ __launch_bounds__(512, 4)
void attn_local(const u16* __restrict__ Qg, const u16* __restrict__ Kg,
                const u16* __restrict__ VTg, u16* __restrict__ Og)
{
    __shared__ __align__(16) u16 Ps[8][32 * PSW];  // 36 KB, wave-private

    const int tid  = threadIdx.x;
    const int lane = tid & 63;
    const int wv   = tid >> 6;          // 0..7
    const int col  = lane & 15;
    const int quad = lane >> 4;

    const int idx = blockIdx.x;
    const int c = idx & 31;
    const int h = (idx >> 5) & 7;
    const int b = idx >> 8;

    const int t0 = c * WW;
    const int wq = wv * 32;             // this wave's 32 queries

    const int sc_lo = (c == 0) ? 4 : 0;                 // kstart >= 0
    const int nsc   = (c == 0 || c == 31) ? 8 : 12;     // kstart < T

    // Q fragments (B-operand): lane holds Q[t0+wq+qi*16+col][kk*32+quad*8..+8]
    bf16x8 qf[2][2];
    {
        const size_t qbase = ((size_t)(b * TT + t0 + wq + col)) * DD + h * DH + quad * 8;
        #pragma unroll
        for (int qi = 0; qi < 2; qi++)
            #pragma unroll
            for (int kk = 0; kk < 2; kk++)
                qf[qi][kk] = *(const bf16x8*)(Qg + qbase + (size_t)qi * 16 * DD + kk * 32);
    }

    f32x4 o[4][2] = {};                 // O^T accum: [di(d-tile)][qi(q-tile)]
    float lsum[2] = {0.f, 0.f};         // per-lane partial l for q=qi*16+col

    u16* psb = &Ps[wv][0];

    // K frag base: row = kstart + ns*16 + col, d-offset quad*8
    const size_t kb0 = ((size_t)(b * TT + col)) * DD + h * DH + quad * 8;
    // VT frag base: row d = di*16+col, key-offset kstart + kt*32 + quad*8
    const size_t vb0 = ((size_t)((b * HH + h) * DH + col)) * TT + quad * 8;

    for (int it = 0; it < nsc; it++) {
        const int kstart = t0 - WW + (sc_lo + it) * 64;

        // S^T[key][q] : A = K fragments straight from global (coalesced)
        f32x4 s[4][2];
        #pragma unroll
        for (int ns = 0; ns < 4; ns++) {
            #pragma unroll
            for (int qi = 0; qi < 2; qi++)
                s[ns][qi] = (f32x4){0.f, 0.f, 0.f, 0.f};
        }
        #pragma unroll
        for (int ns = 0; ns < 4; ns++) {
            const u16* kp = Kg + kb0 + (size_t)(kstart + ns * 16) * DD;
            bf16x8 ka0 = *(const bf16x8*)(kp);
            bf16x8 ka1 = *(const bf16x8*)(kp + 32);
            #pragma unroll
            for (int qi = 0; qi < 2; qi++) {
                s[ns][qi] = mfma16(ka0, qf[qi][0], s[ns][qi]);
                s[ns][qi] = mfma16(ka1, qf[qi][1], s[ns][qi]);
            }
        }

        // p = exp(s/8), accumulate l (fp32, pre-rounding), pack -> b64 write
        #pragma unroll
        for (int ns = 0; ns < 4; ns++) {
            #pragma unroll
            for (int qi = 0; qi < 2; qi++) {
                u16 pb[4];
                #pragma unroll
                for (int r = 0; r < 4; r++) {
                    const float p = __expf(s[ns][qi][r] * 0.125f);
                    pb[r] = f2b(p);
                    lsum[qi] += p;
                }
                uint2 pk;
                pk.x = pb[0] | ((u32)pb[1] << 16);
                pk.y = pb[2] | ((u32)pb[3] << 16);
                *(uint2*)&psb[(qi * 16 + col) * PSW + ns * 16 + quad * 4] = pk;
            }
        }
        asm volatile("" ::: "memory");   // order Ps write -> read (wave-private)

        // O^T += VT . P : A = VT fragments straight from global (coalesced)
        #pragma unroll
        for (int kt = 0; kt < 2; kt++) {
            bf16x8 pf[2];
            #pragma unroll
            for (int qi = 0; qi < 2; qi++)
                pf[qi] = ldsfrag(&psb[(qi * 16 + col) * PSW + kt * 32 + quad * 8]);
            #pragma unroll
            for (int di = 0; di < 4; di++) {
                const u16* vp = VTg + vb0 + (size_t)(di * 16) * TT + kstart + kt * 32;
                bf16x8 va = *(const bf16x8*)vp;
                #pragma unroll
                for (int qi = 0; qi < 2; qi++)
                    o[di][qi] = mfma16(va, pf[qi], o[di][qi]);
            }
        }
    }

    // final l reduction over quads (lanes col,col+16,col+32,col+48 share q)
    #pragma unroll
    for (int qi = 0; qi < 2; qi++) {
        float l = lsum[qi];
        l += __shfl_xor(l, 16);
        l += __shfl_xor(l, 32);
        lsum[qi] = 1.0f / l;
    }

    // store O^T: element (di,qi,r): d = di*16+quad*4+r, q = qi*16+col
    #pragma unroll
    for (int qi = 0; qi < 2; qi++) {
        const size_t ob = ((size_t)(b * TT + t0 + wq + qi * 16 + col)) * DD + h * DH + quad * 4;
        #pragma unroll
        for (int di = 0; di < 4; di++) {
            u16 pb[4];
            #pragma unroll
            for (int r = 0; r < 4; r++) pb[r] = f2b(o[di][qi][r] * lsum[qi]);
            uint2 pk;
            pk.x = pb[0] | ((u32)pb[1] << 16);
            pk.y = pb[2] | ((u32)pb[3] << 16);
            *(uint2*)&Og[ob + di * 16] = pk;
        }
    }
}

extern "C" void kernel_launch(void* const* d_in, const int* in_sizes, int n_in,
                              void* d_out, int out_size, void* d_ws, size_t ws_size,
                              hipStream_t stream)
{
    u16* ws   = (u16*)d_ws;
    u16* xb   = ws;                       // NX
    u16* Wcat = xb + NX;                  // 3*NW  (Wq,Wk,Wv rows concatenated)
    u16* Wob  = Wcat + 3 * NW;            // NW
    u16* bcat = Wob + NW;                 // 1536
    u16* bob  = bcat + 1536;              // 512
    u16* qws  = bob + 512;                // NX   Q  [b*T+t][h*64+d]
    u16* kws  = qws + NX;                 // NX   K  same
    u16* vtws = kws + NX;                 // NX   V^T [(b*8+h)*64+d][t]
    u16* aws  = vtws + NX;                // NX   attn out [b*T+t][h*64+d]
    int* flag = (int*)(aws + NX);

    // 9439232 elements / 8 per thread / 256 per block = 4609 blocks
    convert_all<<<4609, 256, 0, stream>>>(
        d_in[0], d_in[1], d_in[2], d_in[3], d_in[4], d_in[5], d_in[6], d_in[7], d_in[8],
        xb, Wcat, Wob, bcat, bob, flag);

    // fused QKV projection: N = 1536 (512-thread blocks)
    gemm128<<<dim3(128, 12), 512, 0, stream>>>(xb, Wcat, bcat, qws, kws, vtws, 0, flag);
    // local attention: 512 blocks x 512 threads, barrier-free
    attn_local<<<dim3(BB * HH * 32), 512, 0, stream>>>(qws, kws, vtws, aws);
    // output projection
    gemm128<<<dim3(128, 4), 512, 0, stream>>>(aws, Wob, bob, d_out, nullptr, nullptr, 1, flag);
}

// Round 7
// 195.234 us; speedup vs baseline: 1.8126x; 1.8126x over previous
//
#include <hip/hip_runtime.h>
#include <hip/hip_bf16.h>

typedef unsigned short u16;
typedef unsigned int   u32;
typedef __bf16 bf16x8 __attribute__((ext_vector_type(8)));
typedef float  f32x4  __attribute__((ext_vector_type(4)));

#define BB 2
#define TT 8192
#define DD 512
#define HH 8
#define WW 256
#define DH 64
#define NX 8388608   // 16384*512
#define NW 262144    // 512*512

__device__ __forceinline__ float b2f(u16 u) {
    unsigned int x = ((unsigned int)u) << 16;
    return __builtin_bit_cast(float, x);
}
__device__ __forceinline__ u16 f2b(float f) {
    __bf16 h = (__bf16)f;
    return __builtin_bit_cast(u16, h);
}
__device__ __forceinline__ bf16x8 ldsfrag(const u16* p) {
    return *(const bf16x8*)p;
}
__device__ __forceinline__ f32x4 mfma16(bf16x8 a, bf16x8 b, f32x4 c) {
    return __builtin_amdgcn_mfma_f32_16x16x32_bf16(a, b, c, 0, 0, 0);
}

typedef __attribute__((address_space(1))) u32 gu32;
typedef __attribute__((address_space(3))) u32 lu32;
// async global->LDS, 16B per lane, dest = wave-uniform base + lane*16
__device__ __forceinline__ void gl_lds(const u16* g, u16* l) {
    __builtin_amdgcn_global_load_lds((gu32*)g, (lu32*)l, 16, 0, 0);
}

// ---- convert inputs to bf16 in workspace (vectorized, 8 elem/thread).
// dtype flag computed per-block from x's first 2048 u16 (deterministic);
// block 0 persists it. If inputs are already bf16 (f==0), the x-copy is
// skipped entirely -- the QKV gemm reads the original x buffer directly.
__device__ __forceinline__ void cvt8(const void* s, u16* d, long i, int f) {
    if (f) {
        const u32* sp = (const u32*)s + i;
        uint4 a = *(const uint4*)(sp);
        uint4 b = *(const uint4*)(sp + 4);
        u16 o[8];
        o[0] = f2b(__builtin_bit_cast(float, a.x));
        o[1] = f2b(__builtin_bit_cast(float, a.y));
        o[2] = f2b(__builtin_bit_cast(float, a.z));
        o[3] = f2b(__builtin_bit_cast(float, a.w));
        o[4] = f2b(__builtin_bit_cast(float, b.x));
        o[5] = f2b(__builtin_bit_cast(float, b.y));
        o[6] = f2b(__builtin_bit_cast(float, b.z));
        o[7] = f2b(__builtin_bit_cast(float, b.w));
        *(uint4*)(d + i) = *(const uint4*)o;
    } else {
        *(uint4*)(d + i) = *(const uint4*)((const u16*)s + i);
    }
}

__global__ void convert_all(const void* x, const void* Wq, const void* bq,
                            const void* Wk, const void* bk, const void* Wv,
                            const void* bv, const void* Wo, const void* bo,
                            u16* __restrict__ xb, u16* __restrict__ Wcat,
                            u16* __restrict__ Wob, u16* __restrict__ bcat,
                            u16* __restrict__ bob, int* __restrict__ flagw)
{
    __shared__ int sflag;
    const int tid = threadIdx.x;
    if (tid == 0) sflag = 0;
    __syncthreads();
    int mybad = 0;
    for (int i = tid; i < 2048; i += 256) {
        float v = b2f(((const u16*)x)[i]);
        if (!(fabsf(v) < 100.f)) mybad = 1;   // fp32 mantissa halves look wild
    }
    if (mybad) atomicOr(&sflag, 1);
    __syncthreads();
    const int f = sflag ? 1 : 0;
    if (blockIdx.x == 0 && tid == 0) *flagw = f;

    long i = ((long)blockIdx.x * 256 + tid) * 8;
    if (i < NX)            { if (f) cvt8(x, xb, i, f); return; }  // skip copy if bf16
    i -= NX;
    if (i < NW)            { cvt8(Wq, Wcat,         i, f); return; }
    i -= NW;
    if (i < NW)            { cvt8(Wk, Wcat + NW,    i, f); return; }
    i -= NW;
    if (i < NW)            { cvt8(Wv, Wcat + 2*NW,  i, f); return; }
    i -= NW;
    if (i < NW)            { cvt8(Wo, Wob,          i, f); return; }
    i -= NW;
    if (i < 512)           { cvt8(bq, bcat,         i, f); return; }
    i -= 512;
    if (i < 512)           { cvt8(bk, bcat + 512,   i, f); return; }
    i -= 512;
    if (i < 512)           { cvt8(bv, bcat + 1024,  i, f); return; }
    i -= 512;
    if (i < 512)           { cvt8(bo, bob,          i, f); }
}

// 128x128-tile GEMM, BK=64, gl_lds staging with XOR swizzle (R5-proven
// structure: 256 thr = 4 waves 2x2 of 64x64). K=512 fixed.
// NEW (R7): swapped-operand epilogue. For row-major outputs (Q/K, O-proj)
// the MFMA computes D(row=n, col=m) via A=W-rows, B=x-rows, so each lane
// holds 4 CONSECUTIVE n for fixed m -> one uint2 (bf16) / uint4 (fp32)
// store instead of 4 scalar u16. V^T blocks (mode 0, blockIdx.y>=8) keep
// the non-swapped layout (contiguous dim there is t = C-col already).
// mode 0 (fused QKV, N=1536): y<8 swapped -> Q,K [t][h*64+d]; y>=8
//   non-swapped -> V^T [(b*8+h)*64+d][t].
// mode 1 (O-proj, swapped): out0, fp32 if *flagp else bf16.
__global__ __launch_bounds__(256, 2)
void gemm128(const u16* __restrict__ A, const u16* __restrict__ Aalt,
             const u16* __restrict__ Bw, const u16* __restrict__ bias,
             void* __restrict__ out0, u16* __restrict__ out1,
             u16* __restrict__ out2, int mode, const int* __restrict__ flagp)
{
    __shared__ __align__(16) u16 AsF[128 * 64];   // x rows (m)
    __shared__ __align__(16) u16 BsF[128 * 64];   // W rows (n)

    const int tid  = threadIdx.x;
    const int lane = tid & 63;
    const int wv   = tid >> 6;
    const int col  = lane & 15;
    const int quad = lane >> 4;
    const int wm   = (wv & 1) * 64;
    const int wn   = (wv >> 1) * 64;
    const int m0   = blockIdx.x * 128;
    const int n0   = blockIdx.y * 128;

    const int f = *flagp;
    const u16* Ap = f ? A : Aalt;       // bf16 inputs: read x directly

    const bool swapped = (mode == 1) || (blockIdx.y < 8);

    f32x4 acc[4][4] = {};   // swapped: [ni][mi] (row=n); else [mi][ni] (row=m)

    for (int k0 = 0; k0 < 512; k0 += 64) {
        __syncthreads();
        #pragma unroll
        for (int i = 0; i < 4; i++) {
            const int r  = (wv * 4 + i) * 8 + (lane >> 3);
            const int cb = (lane & 7) ^ (r & 7);
            gl_lds(Ap + (size_t)(m0 + r) * 512 + k0 + cb * 8, &AsF[(wv * 4 + i) * 512]);
            gl_lds(Bw + (size_t)(n0 + r) * 512 + k0 + cb * 8, &BsF[(wv * 4 + i) * 512]);
        }
        __syncthreads();
        #pragma unroll
        for (int kk = 0; kk < 2; kk++) {
            bf16x8 fx[4], fw[4];
            #pragma unroll
            for (int mi = 0; mi < 4; mi++)
                fx[mi] = ldsfrag(&AsF[(wm + mi * 16 + col) * 64 + ((kk * 4 + quad) ^ (col & 7)) * 8]);
            #pragma unroll
            for (int ni = 0; ni < 4; ni++)
                fw[ni] = ldsfrag(&BsF[(wn + ni * 16 + col) * 64 + ((kk * 4 + quad) ^ (col & 7)) * 8]);
            if (swapped) {
                #pragma unroll
                for (int ni = 0; ni < 4; ni++)
                    #pragma unroll
                    for (int mi = 0; mi < 4; mi++)
                        acc[ni][mi] = mfma16(fw[ni], fx[mi], acc[ni][mi]);
            } else {
                #pragma unroll
                for (int mi = 0; mi < 4; mi++)
                    #pragma unroll
                    for (int ni = 0; ni < 4; ni++)
                        acc[mi][ni] = mfma16(fx[mi], fw[ni], acc[mi][ni]);
            }
        }
    }

    if (swapped) {
        // D(row = n-local = wn+ni*16+quad*4+r, col = m-local = wm+mi*16+col)
        const int outf32 = (mode == 1) && f;
        #pragma unroll
        for (int mi = 0; mi < 4; mi++) {
            const int gm = m0 + wm + mi * 16 + col;
            #pragma unroll
            for (int ni = 0; ni < 4; ni++) {
                const int gn = n0 + wn + ni * 16 + quad * 4;
                uint2 bv2 = *(const uint2*)(bias + gn);
                const u16* bp = (const u16*)&bv2;
                float v[4];
                #pragma unroll
                for (int r = 0; r < 4; r++) v[r] = acc[ni][mi][r] + b2f(bp[r]);
                if (mode == 1) {
                    if (outf32) {
                        uint4 pk;
                        pk.x = __builtin_bit_cast(u32, v[0]);
                        pk.y = __builtin_bit_cast(u32, v[1]);
                        pk.z = __builtin_bit_cast(u32, v[2]);
                        pk.w = __builtin_bit_cast(u32, v[3]);
                        *(uint4*)&((float*)out0)[(size_t)gm * 512 + gn] = pk;
                    } else {
                        uint2 pk;
                        pk.x = f2b(v[0]) | ((u32)f2b(v[1]) << 16);
                        pk.y = f2b(v[2]) | ((u32)f2b(v[3]) << 16);
                        *(uint2*)&((u16*)out0)[(size_t)gm * 512 + gn] = pk;
                    }
                } else {
                    u16* dst = (gn < 512) ? (u16*)out0 : out1;
                    uint2 pk;
                    pk.x = f2b(v[0]) | ((u32)f2b(v[1]) << 16);
                    pk.y = f2b(v[2]) | ((u32)f2b(v[3]) << 16);
                    *(uint2*)&dst[(size_t)gm * 512 + (gn & 511)] = pk;
                }
            }
        }
    } else {
        // V^T output: D(row = m-local (t), col = n-local (d)) -- uint2 over t
        #pragma unroll
        for (int ni = 0; ni < 4; ni++) {
            const int gn = n0 + wn + ni * 16 + col;     // 1024..1535
            const float bv = b2f(bias[gn]);
            const int d = gn & 63, hh = (gn >> 6) & 7;
            #pragma unroll
            for (int mi = 0; mi < 4; mi++) {
                const int gmb = m0 + wm + mi * 16 + quad * 4;
                const int bb = gmb >> 13, t = gmb & 8191;
                u16 pb[4];
                #pragma unroll
                for (int r = 0; r < 4; r++) pb[r] = f2b(acc[mi][ni][r] + bv);
                uint2 pk;
                pk.x = pb[0] | ((u32)pb[1] << 16);
                pk.y = pb[2] | ((u32)pb[3] << 16);
                *(uint2*)&out2[((size_t)(bb * 8 + hh) * 64 + d) * 8192 + t] = pk;
            }
        }
    }
}

// Local attention (R5-proven): block = (b,h,chunk), 8 waves x 32 queries
// (512 threads). Double-buffered 64-key sub-chunks over [c-1,c,c+1];
// contiguous valid range, one barrier per iteration, prefetch in flight
// across compute. No max-subtraction (scores O(6), softmax shift-invariant).
// S^T = K.Q^T so P packs to LDS as b64; O^T = VT.P so normalization is
// per-lane and stores pack as 8B. V input is pre-transposed [b,h,d][t].
#define PSW 72
__global__ __launch_bounds__(512, 4)
void attn_local(const u16* __restrict__ Qg, const u16* __restrict__ Kg,
                const u16* __restrict__ VTg, u16* __restrict__ Og)
{
    __shared__ __align__(16) u16 Ks[2][64 * 64];   // 16 KB
    __shared__ __align__(16) u16 VTs[2][64 * 64];  // 16 KB
    __shared__ __align__(16) u16 Ps[8][32 * PSW];  // 36 KB (wave-private)

    const int tid  = threadIdx.x;
    const int lane = tid & 63;
    const int wv   = tid >> 6;          // 0..7
    const int col  = lane & 15;
    const int quad = lane >> 4;

    const int idx = blockIdx.x;
    const int c = idx & 31;
    const int h = (idx >> 5) & 7;
    const int b = idx >> 8;

    const int t0 = c * WW;
    const int wq = wv * 32;             // this wave's 32 queries

    const int sc_lo = (c == 0) ? 4 : 0;                 // kstart >= 0
    const int nsc   = (c == 0 || c == 31) ? 8 : 12;     // kstart < T

    const int ldr = lane >> 3;            // staging row-within-group (0..7)
    const int ldc = lane & 7;

    // Q fragments (B-operand): lane holds Q[t0+wq+qi*16+col][kk*32+quad*8..+8]
    bf16x8 qf[2][2];
    {
        const size_t qbase = ((size_t)(b * TT + t0 + wq + col)) * DD + h * DH + quad * 8;
        #pragma unroll
        for (int qi = 0; qi < 2; qi++)
            #pragma unroll
            for (int kk = 0; kk < 2; kk++)
                qf[qi][kk] = *(const bf16x8*)(Qg + qbase + (size_t)qi * 16 * DD + kk * 32);
    }

    f32x4 o[4][2] = {};                 // O^T accum: [di(d-tile)][qi(q-tile)]
    float lsum[2] = {0.f, 0.f};         // per-lane partial l for q=qi*16+col

    u16* psb = &Ps[wv][0];

    // prefetch first sub-chunk into buf 0 (one K + one VT row-group per wave)
    {
        const int kstart = t0 - WW + sc_lo * 64;
        const int rr = wv * 8 + ldr;
        const int cb = ldc ^ (rr & 7);
        gl_lds(Kg  + ((size_t)(b * TT + kstart + rr)) * DD + h * DH + cb * 8,
               &Ks[0][wv * 512]);
        gl_lds(VTg + ((size_t)((b * HH + h) * DH + rr)) * TT + kstart + cb * 8,
               &VTs[0][wv * 512]);
    }

    for (int it = 0; it < nsc; it++) {
        __syncthreads();   // drains loads for buf it&1; prev readers of other buf done
        if (it + 1 < nsc) {
            const int kstart = t0 - WW + (sc_lo + it + 1) * 64;
            const int buf = (it + 1) & 1;
            const int rr = wv * 8 + ldr;
            const int cb = ldc ^ (rr & 7);
            gl_lds(Kg  + ((size_t)(b * TT + kstart + rr)) * DD + h * DH + cb * 8,
                   &Ks[buf][wv * 512]);
            gl_lds(VTg + ((size_t)((b * HH + h) * DH + rr)) * TT + kstart + cb * 8,
                   &VTs[buf][wv * 512]);
        }
        const u16* ks = &Ks[it & 1][0];
        const u16* vs = &VTs[it & 1][0];

        // S^T[key][q] : A = K rows, B = Q rows (32 queries per wave)
        f32x4 s[4][2];
        #pragma unroll
        for (int ns = 0; ns < 4; ns++)
            #pragma unroll
            for (int qi = 0; qi < 2; qi++)
                s[ns][qi] = (f32x4){0.f, 0.f, 0.f, 0.f};
        #pragma unroll
        for (int ns = 0; ns < 4; ns++) {
            const int row = ns * 16 + col;
            bf16x8 ka0 = ldsfrag(&ks[row * 64 + ((0 + quad) ^ (col & 7)) * 8]);
            bf16x8 ka1 = ldsfrag(&ks[row * 64 + ((4 + quad) ^ (col & 7)) * 8]);
            #pragma unroll
            for (int qi = 0; qi < 2; qi++) {
                s[ns][qi] = mfma16(ka0, qf[qi][0], s[ns][qi]);
                s[ns][qi] = mfma16(ka1, qf[qi][1], s[ns][qi]);
            }
        }

        // p = exp(s/8), accumulate l (fp32, pre-rounding), pack -> b64 write
        #pragma unroll
        for (int ns = 0; ns < 4; ns++) {
            #pragma unroll
            for (int qi = 0; qi < 2; qi++) {
                u16 pb[4];
                #pragma unroll
                for (int r = 0; r < 4; r++) {
                    const float p = __expf(s[ns][qi][r] * 0.125f);
                    pb[r] = f2b(p);
                    lsum[qi] += p;
                }
                uint2 pk;
                pk.x = pb[0] | ((u32)pb[1] << 16);
                pk.y = pb[2] | ((u32)pb[3] << 16);
                *(uint2*)&psb[(qi * 16 + col) * PSW + ns * 16 + quad * 4] = pk;
            }
        }
        asm volatile("" ::: "memory");   // order Ps write -> read (wave-private)

        // O^T += VT . P : A = VT (m=d), B = Ps rows (n=q)
        #pragma unroll
        for (int kt = 0; kt < 2; kt++) {
            bf16x8 pf[2];
            #pragma unroll
            for (int qi = 0; qi < 2; qi++)
                pf[qi] = ldsfrag(&psb[(qi * 16 + col) * PSW + kt * 32 + quad * 8]);
            #pragma unroll
            for (int di = 0; di < 4; di++) {
                bf16x8 va = ldsfrag(&vs[(di * 16 + col) * 64 + ((kt * 4 + quad) ^ (col & 7)) * 8]);
                #pragma unroll
                for (int qi = 0; qi < 2; qi++)
                    o[di][qi] = mfma16(va, pf[qi], o[di][qi]);
            }
        }
    }

    // final l reduction over quads (lanes col,col+16,col+32,col+48 share q)
    #pragma unroll
    for (int qi = 0; qi < 2; qi++) {
        float l = lsum[qi];
        l += __shfl_xor(l, 16);
        l += __shfl_xor(l, 32);
        lsum[qi] = 1.0f / l;
    }

    // store O^T: element (di,qi,r): d = di*16+quad*4+r, q = qi*16+col
    #pragma unroll
    for (int qi = 0; qi < 2; qi++) {
        const size_t ob = ((size_t)(b * TT + t0 + wq + qi * 16 + col)) * DD + h * DH + quad * 4;
        #pragma unroll
        for (int di = 0; di < 4; di++) {
            u16 pb[4];
            #pragma unroll
            for (int r = 0; r < 4; r++) pb[r] = f2b(o[di][qi][r] * lsum[qi]);
            uint2 pk;
            pk.x = pb[0] | ((u32)pb[1] << 16);
            pk.y = pb[2] | ((u32)pb[3] << 16);
            *(uint2*)&Og[ob + di * 16] = pk;
        }
    }
}

extern "C" void kernel_launch(void* const* d_in, const int* in_sizes, int n_in,
                              void* d_out, int out_size, void* d_ws, size_t ws_size,
                              hipStream_t stream)
{
    u16* ws   = (u16*)d_ws;
    u16* xb   = ws;                       // NX (used only when inputs are fp32)
    u16* Wcat = xb + NX;                  // 3*NW  (Wq,Wk,Wv rows concatenated)
    u16* Wob  = Wcat + 3 * NW;            // NW
    u16* bcat = Wob + NW;                 // 1536
    u16* bob  = bcat + 1536;              // 512
    u16* qws  = bob + 512;                // NX   Q  [b*T+t][h*64+d]
    u16* kws  = qws + NX;                 // NX   K  same
    u16* vtws = kws + NX;                 // NX   V^T [(b*8+h)*64+d][t]
    u16* aws  = vtws + NX;                // NX   attn out [b*T+t][h*64+d]
    int* flag = (int*)(aws + NX);

    // 9439232 elements / 8 per thread / 256 per block = 4609 blocks
    convert_all<<<4609, 256, 0, stream>>>(
        d_in[0], d_in[1], d_in[2], d_in[3], d_in[4], d_in[5], d_in[6], d_in[7], d_in[8],
        xb, Wcat, Wob, bcat, bob, flag);

    // fused QKV projection: N = 1536 (A = xb if fp32 else raw x)
    gemm128<<<dim3(128, 12), 256, 0, stream>>>(
        xb, (const u16*)d_in[0], Wcat, bcat, qws, kws, vtws, 0, flag);
    // local attention: 512 blocks x 512 threads
    attn_local<<<dim3(BB * HH * 32), 512, 0, stream>>>(qws, kws, vtws, aws);
    // output projection
    gemm128<<<dim3(128, 4), 256, 0, stream>>>(
        aws, aws, Wob, bob, d_out, nullptr, nullptr, 1, flag);
}